// Round 8
// baseline (239.813 us; speedup 1.0000x reference)
//
#include <hip/hip_runtime.h>
#include <hip/hip_bf16.h>

typedef unsigned short u16;
typedef unsigned int u32;
typedef __attribute__((ext_vector_type(8))) short short8;   // 8 bf16 (4 VGPRs) MFMA operand
typedef __attribute__((ext_vector_type(4))) float f32x4;    // MFMA 16x16 accumulator

#define T_TOK 32768
#define SCALE_ATT 0.17677669529663687f   // 32^-0.5

__device__ __forceinline__ u16 f2bf(float f){
  u32 u = __float_as_uint(f);
  u32 r = u + 0x7fffu + ((u >> 16) & 1u);   // RTN-even
  return (u16)(r >> 16);
}
__device__ __forceinline__ float bf2f(u16 h){
  return __uint_as_float(((u32)h) << 16);
}

// ---------------- fp32 -> bf16 convert (qkv_w, proj_w) ----------------
__global__ void k_cvt(const float* __restrict__ s, u16* __restrict__ d, int n4){
  int i = blockIdx.x * blockDim.x + threadIdx.x;
  if (i < n4){
    float4 v = ((const float4*)s)[i];
    ushort4 o;
    o.x = f2bf(v.x); o.y = f2bf(v.y); o.z = f2bf(v.z); o.w = f2bf(v.w);
    ((ushort4*)d)[i] = o;
  }
}

// split fp32 -> (hi, lo) bf16 pair: v = hi + lo + O(2^-18 v). For router w1.
__global__ void k_cvt_split(const float* __restrict__ s, u16* __restrict__ hi,
                            u16* __restrict__ lo, int n){
  int i = blockIdx.x * blockDim.x + threadIdx.x;
  if (i < n){
    float v = s[i];
    u16 h = f2bf(v);
    hi[i] = h;
    lo[i] = f2bf(v - bf2f(h));    // v - hi exact in fp32 (shared high bits)
  }
}

__global__ void k_init(int* counts, int* cursors){
  int t = threadIdx.x;
  if (t < 8){ counts[t] = 0; cursors[t] = 0; }
}

// ---------------- MFMA router (split-bf16 "bf16x3") ----------------
// h = relu(x@w1^T+b1) via MFMA: x=x_hi+x_lo, w1=w1_hi+w1_lo (bf16 pairs);
// h ~ hi*hi + hi*lo + lo*hi in fp32 accum -> logit err ~1e-6 << top-2 gap
// ~1e-2 -> routes match fp32. Logits+softmax+argmax stay fp32 VALU (67 MF).
__global__ __launch_bounds__(256) void k_router(
    const float* __restrict__ x, const u16* __restrict__ w1h, const u16* __restrict__ w1l,
    const float* __restrict__ b1, const float* __restrict__ w2, const float* __restrict__ b2,
    int* __restrict__ routes, float* __restrict__ pmax, int* __restrict__ counts,
    u16* __restrict__ x_bf)
{
  __shared__ __align__(16) char smem[64*132*4];   // 33792 B
  u16* Ah = (u16*)smem;          // 64 x 40
  u16* Al = Ah + 2560;           // 64 x 40
  u16* Bh = Al + 2560;           // 128 x 40
  u16* Bl = Bh + 5120;           // 128 x 40
  float* Hs = (float*)smem;      // overlay after MFMA: 64 x 132
  __shared__ int lhist[8];

  int tid = threadIdx.x;
  int t0 = blockIdx.x * 64;
  int wv = tid >> 6, lane = tid & 63, quad = lane >> 4, l16 = lane & 15;
  if (tid < 8) lhist[tid] = 0;

  int arow = tid >> 2, acg = tid & 3;        // A staging: 64 rows x 4 col-groups of 8
  int brow = tid >> 1, bhalf = tid & 1;      // B staging: 128 rows x 2 halves of 16

  f32x4 acc[4][2];
  #pragma unroll
  for (int i = 0; i < 4; ++i)
    #pragma unroll
    for (int j = 0; j < 2; ++j)
      #pragma unroll
      for (int rr = 0; rr < 4; ++rr) acc[i][j][rr] = 0.f;

  for (int kt = 0; kt < 8; ++kt){
    // global loads
    const float* gx = x + (size_t)(t0 + arow) * 256 + kt * 32 + acg * 8;
    float4 v0 = *(const float4*)gx;
    float4 v1 = *(const float4*)(gx + 4);
    ushort4 h0, h1, l0, l1;
    h0.x = f2bf(v0.x); h0.y = f2bf(v0.y); h0.z = f2bf(v0.z); h0.w = f2bf(v0.w);
    h1.x = f2bf(v1.x); h1.y = f2bf(v1.y); h1.z = f2bf(v1.z); h1.w = f2bf(v1.w);
    l0.x = f2bf(v0.x - bf2f(h0.x)); l0.y = f2bf(v0.y - bf2f(h0.y));
    l0.z = f2bf(v0.z - bf2f(h0.z)); l0.w = f2bf(v0.w - bf2f(h0.w));
    l1.x = f2bf(v1.x - bf2f(h1.x)); l1.y = f2bf(v1.y - bf2f(h1.y));
    l1.z = f2bf(v1.z - bf2f(h1.z)); l1.w = f2bf(v1.w - bf2f(h1.w));
    u16* gxb = x_bf + (size_t)(t0 + arow) * 256 + kt * 32 + acg * 8;
    *(ushort4*)gxb = h0; *(ushort4*)(gxb + 4) = h1;
    const u16* gwh = w1h + (size_t)brow * 256 + kt * 32 + bhalf * 16;
    const u16* gwl = w1l + (size_t)brow * 256 + kt * 32 + bhalf * 16;
    uint4 wh0 = *(const uint4*)gwh;
    uint4 wh1 = *(const uint4*)(gwh + 8);
    uint4 wl0 = *(const uint4*)gwl;
    uint4 wl1 = *(const uint4*)(gwl + 8);
    __syncthreads();
    *(ushort4*)&Ah[arow*40 + acg*8    ] = h0;
    *(ushort4*)&Ah[arow*40 + acg*8 + 4] = h1;
    *(ushort4*)&Al[arow*40 + acg*8    ] = l0;
    *(ushort4*)&Al[arow*40 + acg*8 + 4] = l1;
    *(uint4*)&Bh[brow*40 + bhalf*16    ] = wh0;
    *(uint4*)&Bh[brow*40 + bhalf*16 + 8] = wh1;
    *(uint4*)&Bl[brow*40 + bhalf*16    ] = wl0;
    *(uint4*)&Bl[brow*40 + bhalf*16 + 8] = wl1;
    __syncthreads();
    short8 ah[4], al[4], bhf[2], blf[2];
    #pragma unroll
    for (int i = 0; i < 4; ++i){
      ah[i] = *(const short8*)&Ah[(i*16 + l16)*40 + quad*8];
      al[i] = *(const short8*)&Al[(i*16 + l16)*40 + quad*8];
    }
    #pragma unroll
    for (int j = 0; j < 2; ++j){
      bhf[j] = *(const short8*)&Bh[(wv*32 + j*16 + l16)*40 + quad*8];
      blf[j] = *(const short8*)&Bl[(wv*32 + j*16 + l16)*40 + quad*8];
    }
    #pragma unroll
    for (int i = 0; i < 4; ++i)
      #pragma unroll
      for (int j = 0; j < 2; ++j){
        acc[i][j] = __builtin_amdgcn_mfma_f32_16x16x32_bf16(ah[i], bhf[j], acc[i][j], 0, 0, 0);
        acc[i][j] = __builtin_amdgcn_mfma_f32_16x16x32_bf16(ah[i], blf[j], acc[i][j], 0, 0, 0);
        acc[i][j] = __builtin_amdgcn_mfma_f32_16x16x32_bf16(al[i], bhf[j], acc[i][j], 0, 0, 0);
      }
  }
  __syncthreads();   // all frag reads done before Hs overlay

  // H -> LDS (fp32), bias + relu. C/D: row=i*16+quad*4+rr, col=wv*32+j*16+l16 [m89]
  #pragma unroll
  for (int i = 0; i < 4; ++i)
    #pragma unroll
    for (int j = 0; j < 2; ++j){
      int col = wv*32 + j*16 + l16;
      float bb = b1[col];
      #pragma unroll
      for (int rr = 0; rr < 4; ++rr){
        float h = acc[i][j][rr] + bb;
        Hs[(i*16 + quad*4 + rr)*132 + col] = h > 0.f ? h : 0.f;
      }
    }
  __syncthreads();

  // logits + softmax: 8 lanes per token (e = tid&7), 32 tokens/pass (fp32)
  #pragma unroll
  for (int pass = 0; pass < 2; ++pass){
    int mtok = (tid >> 3) + pass * 32;
    int e = tid & 7;
    const float4* w2r = (const float4*)(w2 + e * 128);
    float l = b2[e];
    #pragma unroll
    for (int k4 = 0; k4 < 32; ++k4){
      float4 w = w2r[k4];
      int k = k4 * 4;
      l = fmaf(Hs[mtok*132+k  ], w.x, l);
      l = fmaf(Hs[mtok*132+k+1], w.y, l);
      l = fmaf(Hs[mtok*132+k+2], w.z, l);
      l = fmaf(Hs[mtok*132+k+3], w.w, l);
    }
    float mv = l; int mi = e;
    #pragma unroll
    for (int off = 1; off < 8; off <<= 1){
      float ov = __shfl_xor(mv, off, 64);
      int   oi = __shfl_xor(mi, off, 64);
      if (ov > mv || (ov == mv && oi < mi)){ mv = ov; mi = oi; }
    }
    float sum = expf(l - mv);
    #pragma unroll
    for (int off = 1; off < 8; off <<= 1) sum += __shfl_xor(sum, off, 64);
    if (e == 0){
      int t = t0 + mtok;
      routes[t] = mi;
      pmax[t] = 1.0f / sum;           // exp(lmax-lmax)/sum
      atomicAdd(&lhist[mi], 1);       // LDS — cheap
    }
  }
  __syncthreads();
  if (tid < 8 && lhist[tid] > 0) atomicAdd(&counts[tid], lhist[tid]);
}

// ---------------- counting-sort machinery ----------------
__global__ void k_offsets(const int* __restrict__ counts, int* __restrict__ offs,
                          int* __restrict__ sorted){
  __shared__ int so[9];
  if (threadIdx.x == 0){
    int o = 0; so[0] = 0;
    for (int e = 0; e < 8; ++e){ o += ((counts[e] + 127) >> 7) << 7; so[e+1] = o; }
    for (int e = 0; e < 9; ++e) offs[e] = so[e];
  }
  __syncthreads();
  for (int e = 0; e < 8; ++e){
    int s = so[e] + counts[e], en = so[e+1];
    for (int i = s + (int)threadIdx.x; i < en; i += (int)blockDim.x) sorted[i] = -1;
  }
}

// Block-aggregated scatter: LDS histogram gives each token a local rank;
// ONE global atomic per (block, expert) reserves the base.
__global__ __launch_bounds__(256) void k_scatter(
    const int* __restrict__ routes, const int* __restrict__ offs,
    int* __restrict__ cursors, int* __restrict__ sorted)
{
  __shared__ int lc[8], lb[8];
  int tid = threadIdx.x;
  int t = blockIdx.x * 256 + tid;
  if (tid < 8) lc[tid] = 0;
  __syncthreads();
  int e = routes[t];
  int rank = atomicAdd(&lc[e], 1);           // LDS atomic
  __syncthreads();
  if (tid < 8 && lc[tid] > 0) lb[tid] = atomicAdd(&cursors[tid], lc[tid]);
  __syncthreads();
  sorted[offs[e] + lb[e] + rank] = t;
}

// ---------------- grouped MoE GEMM: out[t] = A[t] @ W[e]^T + bias[e] ----------------
// R7 counters (52.5us each, MfmaUtil 9%, VALU 8%, HBM 26%): latency-bound.
// Fix 1: register-prefetch pipeline — load k-tile kt+1 into regs right after the
//   store barrier of kt so global latency overlaps frag reads + 16 MFMAs.
// Fix 2: column-permuted B staging — global B row inv(r)=(r>>4)+(r&15)*4 staged at
//   LDS row r, so frag j of lane l16 holds output col l16*4+j (contiguous) ->
//   epilogue is 16 uint2 (qkv) / 16 coalesced float4 (proj) stores vs 64 scalar.
#define ASTR 56   // LDS row stride (elems): 112B, 16B-aligned, ~2-way banking on frag reads
template<int NOUT, bool PROJ>
__global__ __launch_bounds__(256) void k_gemm(
    const u16* __restrict__ A, const u16* __restrict__ W,
    const float* __restrict__ bias, const int* __restrict__ sidx,
    const int* __restrict__ offs, const float* __restrict__ pmax,
    u16* __restrict__ outb, float* __restrict__ outf)
{
  __shared__ __align__(16) u16 As[128 * ASTR];
  __shared__ __align__(16) u16 Bs[128 * ASTR];
  int tid = threadIdx.x;
  int m0 = blockIdx.y * 128;
  int n0 = blockIdx.x * 128;
  int total = offs[8];
  if (m0 >= total) return;
  int e = 0;
  #pragma unroll
  for (int i = 1; i < 8; ++i) if (m0 >= offs[i]) e = i;

  int wv = tid >> 6, lane = tid & 63, quad = lane >> 4, l16 = lane & 15;
  int wrow = (wv >> 1) * 64, wcol = (wv & 1) * 64;

  int sm = tid & 127, part = tid >> 7;
  int tokA = sidx[m0 + sm];
  const u16* arow = A + (size_t)(tokA < 0 ? 0 : tokA) * 256 + part * 16;
  int rb = tid & 127;                 // LDS row for B
  int r64 = rb & 63;
  int bcol = n0 + (rb >> 6) * 64 + (r64 >> 4) + (r64 & 15) * 4;   // inv-perm column
  const u16* brow = W + ((size_t)e * NOUT + bcol) * 256 + part * 16;

  f32x4 acc[4][4];
  #pragma unroll
  for (int i = 0; i < 4; ++i)
    #pragma unroll
    for (int j = 0; j < 4; ++j)
      #pragma unroll
      for (int r = 0; r < 4; ++r) acc[i][j][r] = 0.f;

  // prologue: prefetch k-tile 0
  uint4 a0 = ((const uint4*)arow)[0], a1 = ((const uint4*)arow)[1];
  uint4 b0 = ((const uint4*)brow)[0], b1 = ((const uint4*)brow)[1];
  if (tokA < 0){ a0.x=a0.y=a0.z=a0.w=0u; a1.x=a1.y=a1.z=a1.w=0u; }

  for (int kt = 0; kt < 8; ++kt){
    __syncthreads();
    *(uint4*)&As[sm*ASTR + part*16    ] = a0;
    *(uint4*)&As[sm*ASTR + part*16 + 8] = a1;
    *(uint4*)&Bs[rb*ASTR + part*16    ] = b0;
    *(uint4*)&Bs[rb*ASTR + part*16 + 8] = b1;
    __syncthreads();
    if (kt < 7){                       // prefetch kt+1; overlaps frag reads + MFMA
      const uint4* ga = (const uint4*)(arow + (kt+1) * 32);
      a0 = ga[0]; a1 = ga[1];
      if (tokA < 0){ a0.x=a0.y=a0.z=a0.w=0u; a1.x=a1.y=a1.z=a1.w=0u; }
      const uint4* gb = (const uint4*)(brow + (kt+1) * 32);
      b0 = gb[0]; b1 = gb[1];
    }
    short8 af[4], bfv[4];
    #pragma unroll
    for (int i = 0; i < 4; ++i)
      af[i] = *(const short8*)&As[(wrow + i*16 + l16)*ASTR + quad*8];
    #pragma unroll
    for (int j = 0; j < 4; ++j)
      bfv[j] = *(const short8*)&Bs[(wcol + j*16 + l16)*ASTR + quad*8];
    #pragma unroll
    for (int i = 0; i < 4; ++i)
      #pragma unroll
      for (int j = 0; j < 4; ++j)
        acc[i][j] = __builtin_amdgcn_mfma_f32_16x16x32_bf16(af[i], bfv[j], acc[i][j], 0, 0, 0);
  }

  // epilogue: frag j of lane l16 = output col n0+wcol+l16*4+j (contiguous)
  float4 bj4 = *(const float4*)&bias[e*NOUT + n0 + wcol + l16*4];
  #pragma unroll
  for (int i = 0; i < 4; ++i){
    #pragma unroll
    for (int ri = 0; ri < 4; ++ri){
      int row = wrow + i*16 + quad*4 + ri;        // C/D: row=quad*4+reg [m89]
      int t = sidx[m0 + row];
      if (t < 0) continue;
      if (PROJ){
        float pm = pmax[t];
        float4 ov;
        ov.x = (acc[i][0][ri] + bj4.x) * pm;
        ov.y = (acc[i][1][ri] + bj4.y) * pm;
        ov.z = (acc[i][2][ri] + bj4.z) * pm;
        ov.w = (acc[i][3][ri] + bj4.w) * pm;
        *(float4*)&outf[(size_t)t * NOUT + n0 + wcol + l16*4] = ov;
      } else {
        uint2 ov;
        ov.x = (u32)f2bf(acc[i][0][ri] + bj4.x) | ((u32)f2bf(acc[i][1][ri] + bj4.y) << 16);
        ov.y = (u32)f2bf(acc[i][2][ri] + bj4.z) | ((u32)f2bf(acc[i][3][ri] + bj4.w) << 16);
        *(uint2*)&outb[(size_t)t * NOUT + n0 + wcol + l16*4] = ov;
      }
    }
  }
}

// ---------------- MFMA windowed attention with 2D RoPE ----------------
// One wave per (window, head): 512 windows x 8 heads = 4096 wave-tasks ->
// grid 2048 x 2 waves.
__global__ __launch_bounds__(128) void k_attn(const u16* __restrict__ qkv,
                                              u16* __restrict__ attn)
{
  __shared__ __align__(16) u16 lds[2][8576];
  int tid = threadIdx.x;
  int w = tid >> 6, lane = tid & 63;
  u16* Qs = &lds[w][0];
  u16* Ks = &lds[w][2560];
  u16* Ps = &lds[w][0];                      // overlay, stride 72
  u16* Vt = &lds[w][5120];

  int wh = blockIdx.x * 2 + w;               // 0..4095 (window*8 + head)
  if (wh >= 4096) return;
  int win = wh >> 3, head = wh & 7;
  int b = win >> 6, wy = (win >> 3) & 7, wx = win & 7;
  int r = lane >> 3, c = lane & 7;           // token coords (lane = token n)
  int tn = b * 4096 + (wy*8 + r) * 64 + (wx*8 + c);
  const u16* base = qkv + (size_t)tn * 768 + head * 32;

  uint4 qa[4], ka[4], va[4];
  #pragma unroll
  for (int i = 0; i < 4; ++i){
    qa[i] = ((const uint4*)(base      ))[i];
    ka[i] = ((const uint4*)(base + 256))[i];
    va[i] = ((const uint4*)(base + 512))[i];
  }
  u32* qu = (u32*)qa; u32* ku = (u32*)ka; u32* vu = (u32*)va;

  // RoPE (fp32 rotate, repack bf16). u32 j holds channel pair (2j, 2j+1).
  #pragma unroll
  for (int j = 0; j < 8; ++j){
    float inv = __expf(-1.1512925465f * (float)j);   // 10000^(-j/8)
    float ah = (float)r * inv, aw = (float)c * inv;
    float ch = cosf(ah), sh = sinf(ah), cw = cosf(aw), sw = sinf(aw);
    u32 v0, v1; float a0, b0;
    v0 = qu[j];   a0 = bf2f((u16)(v0 & 0xffff)); b0 = bf2f((u16)(v0 >> 16));
    qu[j]   = (u32)f2bf(a0*ch - b0*sh) | ((u32)f2bf(a0*sh + b0*ch) << 16);
    v1 = qu[8+j]; a0 = bf2f((u16)(v1 & 0xffff)); b0 = bf2f((u16)(v1 >> 16));
    qu[8+j] = (u32)f2bf(a0*cw - b0*sw) | ((u32)f2bf(a0*sw + b0*cw) << 16);
    v0 = ku[j];   a0 = bf2f((u16)(v0 & 0xffff)); b0 = bf2f((u16)(v0 >> 16));
    ku[j]   = (u32)f2bf(a0*ch - b0*sh) | ((u32)f2bf(a0*sh + b0*ch) << 16);
    v1 = ku[8+j]; a0 = bf2f((u16)(v1 & 0xffff)); b0 = bf2f((u16)(v1 >> 16));
    ku[8+j] = (u32)f2bf(a0*cw - b0*sw) | ((u32)f2bf(a0*sw + b0*cw) << 16);
  }

  // stage Q,K rows (lane = row n), stride 40 u16 (80B, 16-aligned)
  #pragma unroll
  for (int i = 0; i < 4; ++i){
    *(uint4*)&Qs[lane*40 + i*8] = qa[i];
    *(uint4*)&Ks[lane*40 + i*8] = ka[i];
  }
  // stage V transposed+permuted: Vt[d][pi(n)] = V[n][d]
  int pn = (lane & 15) * 4 + (lane >> 4);
  #pragma unroll
  for (int d2 = 0; d2 < 16; ++d2){
    Vt[(2*d2  )*72 + pn] = (u16)(vu[d2] & 0xffff);
    Vt[(2*d2+1)*72 + pn] = (u16)(vu[d2] >> 16);
  }
  // ones rows 32..47 (row-sum trick)
  uint4 ones = {0x3F803F80u, 0x3F803F80u, 0x3F803F80u, 0x3F803F80u};
  *(uint4*)&Vt[(32 + (lane >> 3))*72 + (lane & 7)*8] = ones;
  *(uint4*)&Vt[(40 + (lane >> 3))*72 + (lane & 7)*8] = ones;

  int quad = lane >> 4, l16 = lane & 15;

  // Q A-frags / K B-frags: frag[m=l16][k=quad*8+j]
  short8 qf[4], kf[4];
  #pragma unroll
  for (int i = 0; i < 4; ++i) qf[i] = *(const short8*)&Qs[(i*16 + l16)*40 + quad*8];
  #pragma unroll
  for (int j = 0; j < 4; ++j) kf[j] = *(const short8*)&Ks[(j*16 + l16)*40 + quad*8];

  f32x4 sa[4][4];
  #pragma unroll
  for (int i = 0; i < 4; ++i)
    #pragma unroll
    for (int j = 0; j < 4; ++j){
      #pragma unroll
      for (int rr = 0; rr < 4; ++rr) sa[i][j][rr] = 0.f;
      sa[i][j] = __builtin_amdgcn_mfma_f32_16x16x32_bf16(qf[i], kf[j], sa[i][j], 0, 0, 0);
    }

  // P = exp(S*scale) -> bf16 -> Ps (overlays Qs/Ks; Q/K frags already in regs).
  // C/D value (i,j,rr): row m=i*16+quad*4+rr, col n=j*16+l16 -> pi(n)=l16*4+j.
  #pragma unroll
  for (int i = 0; i < 4; ++i)
    #pragma unroll
    for (int rr = 0; rr < 4; ++rr){
      float e0 = __expf(sa[i][0][rr] * SCALE_ATT);
      float e1 = __expf(sa[i][1][rr] * SCALE_ATT);
      float e2 = __expf(sa[i][2][rr] * SCALE_ATT);
      float e3 = __expf(sa[i][3][rr] * SCALE_ATT);
      uint2 pk;
      pk.x = (u32)f2bf(e0) | ((u32)f2bf(e1) << 16);
      pk.y = (u32)f2bf(e2) | ((u32)f2bf(e3) << 16);
      *(uint2*)&Ps[(i*16 + quad*4 + rr)*72 + l16*4] = pk;
    }

  // PV: P A-frags from Ps, V B-frags from Vt (both in pi-space), 2 k-steps of 32.
  f32x4 oa[4][2], os[4];
  #pragma unroll
  for (int i = 0; i < 4; ++i){
    #pragma unroll
    for (int rr = 0; rr < 4; ++rr){ oa[i][0][rr] = 0.f; oa[i][1][rr] = 0.f; os[i][rr] = 0.f; }
  }
  #pragma unroll
  for (int ks = 0; ks < 2; ++ks){
    short8 vf0 = *(const short8*)&Vt[(     l16)*72 + ks*32 + quad*8];
    short8 vf1 = *(const short8*)&Vt[(16 + l16)*72 + ks*32 + quad*8];
    short8 vf2 = *(const short8*)&Vt[(32 + l16)*72 + ks*32 + quad*8];
    #pragma unroll
    for (int i = 0; i < 4; ++i){
      short8 pf = *(const short8*)&Ps[(i*16 + l16)*72 + ks*32 + quad*8];
      oa[i][0] = __builtin_amdgcn_mfma_f32_16x16x32_bf16(pf, vf0, oa[i][0], 0, 0, 0);
      oa[i][1] = __builtin_amdgcn_mfma_f32_16x16x32_bf16(pf, vf1, oa[i][1], 0, 0, 0);
      os[i]    = __builtin_amdgcn_mfma_f32_16x16x32_bf16(pf, vf2, os[i],    0, 0, 0);
    }
  }

  // epilogue: O[m][d] = oa/rowsum; store bf16
  int tb = b * 4096 + wy * 512 + wx * 8;
  #pragma unroll
  for (int i = 0; i < 4; ++i)
    #pragma unroll
    for (int rr = 0; rr < 4; ++rr){
      float inv = __builtin_amdgcn_rcpf(os[i][rr]);
      int m = i*16 + quad*4 + rr;
      int tm = tb + (m >> 3) * 64 + (m & 7);
      u16* op = attn + (size_t)tm * 256 + head * 32 + l16;
      op[0]  = f2bf(oa[i][0][rr] * inv);
      op[16] = f2bf(oa[i][1][rr] * inv);
    }
}

// ---------------- launch ----------------
extern "C" void kernel_launch(void* const* d_in, const int* in_sizes, int n_in,
                              void* d_out, int out_size, void* d_ws, size_t ws_size,
                              hipStream_t stream){
  const float* x     = (const float*)d_in[0];
  const float* rw1   = (const float*)d_in[1];
  const float* rb1   = (const float*)d_in[2];
  const float* rw2   = (const float*)d_in[3];
  const float* rb2   = (const float*)d_in[4];
  const float* qkvw  = (const float*)d_in[5];
  const float* qkvb  = (const float*)d_in[6];
  const float* projw = (const float*)d_in[7];
  const float* projb = (const float*)d_in[8];
  float* out = (float*)d_out;

  char* ws = (char*)d_ws;
  u16*   x_bf    = (u16*)(ws);                       // 16,777,216 B
  u16*   qkv_bf  = (u16*)(ws + 16777216);            // 50,331,648 B
  u16*   attn_bf = (u16*)(ws + 67108864);            // 16,777,216 B
  u16*   qw_bf   = (u16*)(ws + 83886080);            //  3,145,728 B
  u16*   pw_bf   = (u16*)(ws + 87031808);            //  1,048,576 B
  int*   routes  = (int*)(ws + 88080384);            //    131,072 B
  float* pmaxp   = (float*)(ws + 88211456);          //    131,072 B
  int*   sorted  = (int*)(ws + 88342528);            //    135,168 B (33792 slots)
  int*   counts  = (int*)(ws + 88477696);
  int*   cursors = (int*)(ws + 88477696 + 32);
  int*   offs    = (int*)(ws + 88477696 + 64);
  // w1 split lives in the attn_bf region (dead until k_attn, long after k_router)
  u16*   w1h     = attn_bf;                          // 65,536 B
  u16*   w1l     = attn_bf + 32768;                  // 65,536 B

  k_init<<<1, 64, 0, stream>>>(counts, cursors);
  k_cvt<<<1536, 256, 0, stream>>>(qkvw,  qw_bf, 1572864/4);
  k_cvt<<< 512, 256, 0, stream>>>(projw, pw_bf,  524288/4);
  k_cvt_split<<<128, 256, 0, stream>>>(rw1, w1h, w1l, 32768);
  k_router<<<512, 256, 0, stream>>>(x, w1h, w1l, rb1, rw2, rb2, routes, pmaxp, counts, x_bf);
  k_offsets<<<1, 256, 0, stream>>>(counts, offs, sorted);
  k_scatter<<<128, 256, 0, stream>>>(routes, offs, cursors, sorted);
  k_gemm<768, false><<<dim3(6, 264), 256, 0, stream>>>(x_bf, qw_bf, qkvb, sorted, offs,
                                                       nullptr, qkv_bf, nullptr);
  k_attn<<<2048, 128, 0, stream>>>(qkv_bf, attn_bf);
  k_gemm<256, true><<<dim3(2, 264), 256, 0, stream>>>(attn_bf, pw_bf, projb, sorted, offs,
                                                      pmaxp, nullptr, out);
}

// Round 9
// 225.604 us; speedup vs baseline: 1.0630x; 1.0630x over previous
//
#include <hip/hip_runtime.h>
#include <hip/hip_bf16.h>

typedef unsigned short u16;
typedef unsigned int u32;
typedef __attribute__((ext_vector_type(8))) short short8;   // 8 bf16 (4 VGPRs) MFMA operand
typedef __attribute__((ext_vector_type(4))) float f32x4;    // MFMA 16x16 accumulator

#define T_TOK 32768
#define SCALE_ATT 0.17677669529663687f   // 32^-0.5

__device__ __forceinline__ u16 f2bf(float f){
  u32 u = __float_as_uint(f);
  u32 r = u + 0x7fffu + ((u >> 16) & 1u);   // RTN-even
  return (u16)(r >> 16);
}
__device__ __forceinline__ float bf2f(u16 h){
  return __uint_as_float(((u32)h) << 16);
}

// ---------------- fp32 -> bf16 convert (qkv_w, proj_w) ----------------
__global__ void k_cvt(const float* __restrict__ s, u16* __restrict__ d, int n4){
  int i = blockIdx.x * blockDim.x + threadIdx.x;
  if (i < n4){
    float4 v = ((const float4*)s)[i];
    ushort4 o;
    o.x = f2bf(v.x); o.y = f2bf(v.y); o.z = f2bf(v.z); o.w = f2bf(v.w);
    ((ushort4*)d)[i] = o;
  }
}

// split fp32 -> (hi, lo) bf16 pair: v = hi + lo + O(2^-18 v). For router w1.
__global__ void k_cvt_split(const float* __restrict__ s, u16* __restrict__ hi,
                            u16* __restrict__ lo, int n){
  int i = blockIdx.x * blockDim.x + threadIdx.x;
  if (i < n){
    float v = s[i];
    u16 h = f2bf(v);
    hi[i] = h;
    lo[i] = f2bf(v - bf2f(h));    // v - hi exact in fp32 (shared high bits)
  }
}

__global__ void k_init(int* counts, int* cursors){
  int t = threadIdx.x;
  if (t < 8){ counts[t] = 0; cursors[t] = 0; }
}

// ---------------- MFMA router (split-bf16 "bf16x3") ----------------
// h = relu(x@w1^T+b1) via MFMA: x=x_hi+x_lo, w1=w1_hi+w1_lo (bf16 pairs);
// h ~ hi*hi + hi*lo + lo*hi in fp32 accum -> logit err ~1e-6 << top-2 gap.
__global__ __launch_bounds__(256) void k_router(
    const float* __restrict__ x, const u16* __restrict__ w1h, const u16* __restrict__ w1l,
    const float* __restrict__ b1, const float* __restrict__ w2, const float* __restrict__ b2,
    int* __restrict__ routes, float* __restrict__ pmax, int* __restrict__ counts,
    u16* __restrict__ x_bf)
{
  __shared__ __align__(16) char smem[64*132*4];   // 33792 B
  u16* Ah = (u16*)smem;          // 64 x 40
  u16* Al = Ah + 2560;           // 64 x 40
  u16* Bh = Al + 2560;           // 128 x 40
  u16* Bl = Bh + 5120;           // 128 x 40
  float* Hs = (float*)smem;      // overlay after MFMA: 64 x 132
  __shared__ int lhist[8];

  int tid = threadIdx.x;
  int t0 = blockIdx.x * 64;
  int wv = tid >> 6, lane = tid & 63, quad = lane >> 4, l16 = lane & 15;
  if (tid < 8) lhist[tid] = 0;

  int arow = tid >> 2, acg = tid & 3;        // A staging: 64 rows x 4 col-groups of 8
  int brow = tid >> 1, bhalf = tid & 1;      // B staging: 128 rows x 2 halves of 16

  f32x4 acc[4][2];
  #pragma unroll
  for (int i = 0; i < 4; ++i)
    #pragma unroll
    for (int j = 0; j < 2; ++j)
      #pragma unroll
      for (int rr = 0; rr < 4; ++rr) acc[i][j][rr] = 0.f;

  for (int kt = 0; kt < 8; ++kt){
    const float* gx = x + (size_t)(t0 + arow) * 256 + kt * 32 + acg * 8;
    float4 v0 = *(const float4*)gx;
    float4 v1 = *(const float4*)(gx + 4);
    ushort4 h0, h1, l0, l1;
    h0.x = f2bf(v0.x); h0.y = f2bf(v0.y); h0.z = f2bf(v0.z); h0.w = f2bf(v0.w);
    h1.x = f2bf(v1.x); h1.y = f2bf(v1.y); h1.z = f2bf(v1.z); h1.w = f2bf(v1.w);
    l0.x = f2bf(v0.x - bf2f(h0.x)); l0.y = f2bf(v0.y - bf2f(h0.y));
    l0.z = f2bf(v0.z - bf2f(h0.z)); l0.w = f2bf(v0.w - bf2f(h0.w));
    l1.x = f2bf(v1.x - bf2f(h1.x)); l1.y = f2bf(v1.y - bf2f(h1.y));
    l1.z = f2bf(v1.z - bf2f(h1.z)); l1.w = f2bf(v1.w - bf2f(h1.w));
    u16* gxb = x_bf + (size_t)(t0 + arow) * 256 + kt * 32 + acg * 8;
    *(ushort4*)gxb = h0; *(ushort4*)(gxb + 4) = h1;
    const u16* gwh = w1h + (size_t)brow * 256 + kt * 32 + bhalf * 16;
    const u16* gwl = w1l + (size_t)brow * 256 + kt * 32 + bhalf * 16;
    uint4 wh0 = *(const uint4*)gwh;
    uint4 wh1 = *(const uint4*)(gwh + 8);
    uint4 wl0 = *(const uint4*)gwl;
    uint4 wl1 = *(const uint4*)(gwl + 8);
    __syncthreads();
    *(ushort4*)&Ah[arow*40 + acg*8    ] = h0;
    *(ushort4*)&Ah[arow*40 + acg*8 + 4] = h1;
    *(ushort4*)&Al[arow*40 + acg*8    ] = l0;
    *(ushort4*)&Al[arow*40 + acg*8 + 4] = l1;
    *(uint4*)&Bh[brow*40 + bhalf*16    ] = wh0;
    *(uint4*)&Bh[brow*40 + bhalf*16 + 8] = wh1;
    *(uint4*)&Bl[brow*40 + bhalf*16    ] = wl0;
    *(uint4*)&Bl[brow*40 + bhalf*16 + 8] = wl1;
    __syncthreads();
    short8 ah[4], al[4], bhf[2], blf[2];
    #pragma unroll
    for (int i = 0; i < 4; ++i){
      ah[i] = *(const short8*)&Ah[(i*16 + l16)*40 + quad*8];
      al[i] = *(const short8*)&Al[(i*16 + l16)*40 + quad*8];
    }
    #pragma unroll
    for (int j = 0; j < 2; ++j){
      bhf[j] = *(const short8*)&Bh[(wv*32 + j*16 + l16)*40 + quad*8];
      blf[j] = *(const short8*)&Bl[(wv*32 + j*16 + l16)*40 + quad*8];
    }
    #pragma unroll
    for (int i = 0; i < 4; ++i)
      #pragma unroll
      for (int j = 0; j < 2; ++j){
        acc[i][j] = __builtin_amdgcn_mfma_f32_16x16x32_bf16(ah[i], bhf[j], acc[i][j], 0, 0, 0);
        acc[i][j] = __builtin_amdgcn_mfma_f32_16x16x32_bf16(ah[i], blf[j], acc[i][j], 0, 0, 0);
        acc[i][j] = __builtin_amdgcn_mfma_f32_16x16x32_bf16(al[i], bhf[j], acc[i][j], 0, 0, 0);
      }
  }
  __syncthreads();   // all frag reads done before Hs overlay

  #pragma unroll
  for (int i = 0; i < 4; ++i)
    #pragma unroll
    for (int j = 0; j < 2; ++j){
      int col = wv*32 + j*16 + l16;
      float bb = b1[col];
      #pragma unroll
      for (int rr = 0; rr < 4; ++rr){
        float h = acc[i][j][rr] + bb;
        Hs[(i*16 + quad*4 + rr)*132 + col] = h > 0.f ? h : 0.f;
      }
    }
  __syncthreads();

  // logits + softmax: 8 lanes per token (e = tid&7), 32 tokens/pass (fp32)
  #pragma unroll
  for (int pass = 0; pass < 2; ++pass){
    int mtok = (tid >> 3) + pass * 32;
    int e = tid & 7;
    const float4* w2r = (const float4*)(w2 + e * 128);
    float l = b2[e];
    #pragma unroll
    for (int k4 = 0; k4 < 32; ++k4){
      float4 w = w2r[k4];
      int k = k4 * 4;
      l = fmaf(Hs[mtok*132+k  ], w.x, l);
      l = fmaf(Hs[mtok*132+k+1], w.y, l);
      l = fmaf(Hs[mtok*132+k+2], w.z, l);
      l = fmaf(Hs[mtok*132+k+3], w.w, l);
    }
    float mv = l; int mi = e;
    #pragma unroll
    for (int off = 1; off < 8; off <<= 1){
      float ov = __shfl_xor(mv, off, 64);
      int   oi = __shfl_xor(mi, off, 64);
      if (ov > mv || (ov == mv && oi < mi)){ mv = ov; mi = oi; }
    }
    float sum = expf(l - mv);
    #pragma unroll
    for (int off = 1; off < 8; off <<= 1) sum += __shfl_xor(sum, off, 64);
    if (e == 0){
      int t = t0 + mtok;
      routes[t] = mi;
      pmax[t] = 1.0f / sum;
      atomicAdd(&lhist[mi], 1);
    }
  }
  __syncthreads();
  if (tid < 8 && lhist[tid] > 0) atomicAdd(&counts[tid], lhist[tid]);
}

// ---------------- counting-sort machinery ----------------
__global__ void k_offsets(const int* __restrict__ counts, int* __restrict__ offs,
                          int* __restrict__ sorted){
  __shared__ int so[9];
  if (threadIdx.x == 0){
    int o = 0; so[0] = 0;
    for (int e = 0; e < 8; ++e){ o += ((counts[e] + 127) >> 7) << 7; so[e+1] = o; }
    for (int e = 0; e < 9; ++e) offs[e] = so[e];
  }
  __syncthreads();
  for (int e = 0; e < 8; ++e){
    int s = so[e] + counts[e], en = so[e+1];
    for (int i = s + (int)threadIdx.x; i < en; i += (int)blockDim.x) sorted[i] = -1;
  }
}

// Block-aggregated scatter; also emits rank[t] = sorted position (for k_attn's
// sorted-order output, so the proj GEMM reads a contiguous A).
__global__ __launch_bounds__(256) void k_scatter(
    const int* __restrict__ routes, const int* __restrict__ offs,
    int* __restrict__ cursors, int* __restrict__ sorted, int* __restrict__ rank)
{
  __shared__ int lc[8], lb[8];
  int tid = threadIdx.x;
  int t = blockIdx.x * 256 + tid;
  if (tid < 8) lc[tid] = 0;
  __syncthreads();
  int e = routes[t];
  int rl = atomicAdd(&lc[e], 1);             // LDS atomic
  __syncthreads();
  if (tid < 8 && lc[tid] > 0) lb[tid] = atomicAdd(&cursors[tid], lc[tid]);
  __syncthreads();
  int pos = offs[e] + lb[e] + rl;
  sorted[pos] = t;
  rank[t] = pos;
}

// ---------------- gather x into sorted order (zero-fill padding) ----------------
// 16 rows/block; 32 lanes read one 512B token row contiguously -> coalesced.
__global__ __launch_bounds__(256) void k_gather(
    const u16* __restrict__ xbf, const int* __restrict__ sorted,
    const int* __restrict__ offs, u16* __restrict__ xs)
{
  int total = offs[8];
  int tid = threadIdx.x;
  #pragma unroll
  for (int h = 0; h < 2; ++h){
    int cid = tid + h * 256;
    int row = cid >> 5, chunk = cid & 31;
    int gr = blockIdx.x * 16 + row;
    int t = (gr < total) ? sorted[gr] : -1;
    uint4 v = {0u, 0u, 0u, 0u};
    if (t >= 0) v = *(const uint4*)(xbf + (size_t)t * 256 + chunk * 8);
    *(uint4*)(xs + (size_t)gr * 256 + chunk * 8) = v;
  }
}

// ---------------- grouped MoE GEMM: out[t] = A_sorted @ W[e]^T + bias[e] ----------------
// R8 post-mortem: transaction-bound (64 scattered 32B chunks per staging instr,
// FETCH 57MB vs 20 ideal). Fix: A pre-gathered (contiguous rows) + chunk-based
// staging — thread (row,chunk): 4 lanes cover one 64B row-slice, 16 full-line
// transactions per wave instr instead of 64 half-used ones. B same pattern
// (rows permuted for the vectorized epilogue: LDS row r holds weight col
// n0+(r>>4)+(r&15)*4 per 64-half, so frag j of lane l16 = output col l16*4+j).
#define ASTR 56   // LDS row stride (elems): 112B, 16B-aligned, 2-way banking
template<int NOUT, bool PROJ>
__global__ __launch_bounds__(256) void k_gemm(
    const u16* __restrict__ A, const u16* __restrict__ W,
    const float* __restrict__ bias, const int* __restrict__ sidx,
    const int* __restrict__ offs, const float* __restrict__ pmax,
    u16* __restrict__ outb, float* __restrict__ outf)
{
  __shared__ __align__(16) u16 As[128 * ASTR];
  __shared__ __align__(16) u16 Bs[128 * ASTR];
  int tid = threadIdx.x;
  int m0 = blockIdx.y * 128;
  int n0 = blockIdx.x * 128;
  int total = offs[8];
  if (m0 >= total) return;
  int e = 0;
  #pragma unroll
  for (int i = 1; i < 8; ++i) if (m0 >= offs[i]) e = i;

  int wv = tid >> 6, lane = tid & 63, quad = lane >> 4, l16 = lane & 15;
  int wrow = (wv >> 1) * 64, wcol = (wv & 1) * 64;

  // chunk staging: thread handles (row0, c0) and (row0+64, c0); 16B each
  int row0 = tid >> 2, c0 = tid & 3;
  const u16* aptr0 = A + (size_t)(m0 + row0) * 256 + c0 * 8;
  const u16* aptr1 = aptr0 + (size_t)64 * 256;
  int pc = (row0 >> 4) + (row0 & 15) * 4;          // permuted col within 64-half
  const u16* bptr0 = W + ((size_t)e * NOUT + n0 + pc) * 256 + c0 * 8;
  const u16* bptr1 = W + ((size_t)e * NOUT + n0 + 64 + pc) * 256 + c0 * 8;

  f32x4 acc[4][4];
  #pragma unroll
  for (int i = 0; i < 4; ++i)
    #pragma unroll
    for (int j = 0; j < 4; ++j)
      #pragma unroll
      for (int r = 0; r < 4; ++r) acc[i][j][r] = 0.f;

  // prologue: prefetch k-tile 0
  uint4 a0 = *(const uint4*)aptr0, a1 = *(const uint4*)aptr1;
  uint4 b0 = *(const uint4*)bptr0, b1 = *(const uint4*)bptr1;

  for (int kt = 0; kt < 8; ++kt){
    __syncthreads();
    *(uint4*)&As[ row0      *ASTR + c0*8] = a0;
    *(uint4*)&As[(row0 + 64)*ASTR + c0*8] = a1;
    *(uint4*)&Bs[ row0      *ASTR + c0*8] = b0;
    *(uint4*)&Bs[(row0 + 64)*ASTR + c0*8] = b1;
    __syncthreads();
    if (kt < 7){                       // prefetch kt+1; overlaps frag reads + MFMA
      a0 = *(const uint4*)(aptr0 + (kt+1)*32);
      a1 = *(const uint4*)(aptr1 + (kt+1)*32);
      b0 = *(const uint4*)(bptr0 + (kt+1)*32);
      b1 = *(const uint4*)(bptr1 + (kt+1)*32);
    }
    short8 af[4], bfv[4];
    #pragma unroll
    for (int i = 0; i < 4; ++i)
      af[i] = *(const short8*)&As[(wrow + i*16 + l16)*ASTR + quad*8];
    #pragma unroll
    for (int j = 0; j < 4; ++j)
      bfv[j] = *(const short8*)&Bs[(wcol + j*16 + l16)*ASTR + quad*8];
    #pragma unroll
    for (int i = 0; i < 4; ++i)
      #pragma unroll
      for (int j = 0; j < 4; ++j)
        acc[i][j] = __builtin_amdgcn_mfma_f32_16x16x32_bf16(af[i], bfv[j], acc[i][j], 0, 0, 0);
  }

  // epilogue: frag j of lane l16 = output col n0+wcol+l16*4+j (contiguous)
  float4 bj4 = *(const float4*)&bias[e*NOUT + n0 + wcol + l16*4];
  #pragma unroll
  for (int i = 0; i < 4; ++i){
    #pragma unroll
    for (int ri = 0; ri < 4; ++ri){
      int row = wrow + i*16 + quad*4 + ri;        // C/D: row=quad*4+reg [m89]
      int t = sidx[m0 + row];
      if (t < 0) continue;
      if (PROJ){
        float pm = pmax[t];
        float4 ov;
        ov.x = (acc[i][0][ri] + bj4.x) * pm;
        ov.y = (acc[i][1][ri] + bj4.y) * pm;
        ov.z = (acc[i][2][ri] + bj4.z) * pm;
        ov.w = (acc[i][3][ri] + bj4.w) * pm;
        *(float4*)&outf[(size_t)t * NOUT + n0 + wcol + l16*4] = ov;
      } else {
        uint2 ov;
        ov.x = (u32)f2bf(acc[i][0][ri] + bj4.x) | ((u32)f2bf(acc[i][1][ri] + bj4.y) << 16);
        ov.y = (u32)f2bf(acc[i][2][ri] + bj4.z) | ((u32)f2bf(acc[i][3][ri] + bj4.w) << 16);
        *(uint2*)&outb[(size_t)t * NOUT + n0 + wcol + l16*4] = ov;
      }
    }
  }
}

// ---------------- MFMA windowed attention with 2D RoPE ----------------
// One wave per (window, head); output written in SORTED order via rank[] so
// the proj GEMM reads a contiguous A.
__global__ __launch_bounds__(128) void k_attn(const u16* __restrict__ qkv,
                                              const int* __restrict__ rank,
                                              u16* __restrict__ attn_s)
{
  __shared__ __align__(16) u16 lds[2][8576];
  int tid = threadIdx.x;
  int w = tid >> 6, lane = tid & 63;
  u16* Qs = &lds[w][0];
  u16* Ks = &lds[w][2560];
  u16* Ps = &lds[w][0];                      // overlay, stride 72
  u16* Vt = &lds[w][5120];

  int wh = blockIdx.x * 2 + w;               // 0..4095 (window*8 + head)
  if (wh >= 4096) return;
  int win = wh >> 3, head = wh & 7;
  int b = win >> 6, wy = (win >> 3) & 7, wx = win & 7;
  int r = lane >> 3, c = lane & 7;           // token coords (lane = token n)
  int tn = b * 4096 + (wy*8 + r) * 64 + (wx*8 + c);
  const u16* base = qkv + (size_t)tn * 768 + head * 32;

  uint4 qa[4], ka[4], va[4];
  #pragma unroll
  for (int i = 0; i < 4; ++i){
    qa[i] = ((const uint4*)(base      ))[i];
    ka[i] = ((const uint4*)(base + 256))[i];
    va[i] = ((const uint4*)(base + 512))[i];
  }
  u32* qu = (u32*)qa; u32* ku = (u32*)ka; u32* vu = (u32*)va;

  // RoPE (fp32 rotate, repack bf16). u32 j holds channel pair (2j, 2j+1).
  #pragma unroll
  for (int j = 0; j < 8; ++j){
    float inv = __expf(-1.1512925465f * (float)j);   // 10000^(-j/8)
    float ah = (float)r * inv, aw = (float)c * inv;
    float ch = cosf(ah), sh = sinf(ah), cw = cosf(aw), sw = sinf(aw);
    u32 v0, v1; float a0, b0;
    v0 = qu[j];   a0 = bf2f((u16)(v0 & 0xffff)); b0 = bf2f((u16)(v0 >> 16));
    qu[j]   = (u32)f2bf(a0*ch - b0*sh) | ((u32)f2bf(a0*sh + b0*ch) << 16);
    v1 = qu[8+j]; a0 = bf2f((u16)(v1 & 0xffff)); b0 = bf2f((u16)(v1 >> 16));
    qu[8+j] = (u32)f2bf(a0*cw - b0*sw) | ((u32)f2bf(a0*sw + b0*cw) << 16);
    v0 = ku[j];   a0 = bf2f((u16)(v0 & 0xffff)); b0 = bf2f((u16)(v0 >> 16));
    ku[j]   = (u32)f2bf(a0*ch - b0*sh) | ((u32)f2bf(a0*sh + b0*ch) << 16);
    v1 = ku[8+j]; a0 = bf2f((u16)(v1 & 0xffff)); b0 = bf2f((u16)(v1 >> 16));
    ku[8+j] = (u32)f2bf(a0*cw - b0*sw) | ((u32)f2bf(a0*sw + b0*cw) << 16);
  }

  // stage Q,K rows (lane = row n), stride 40 u16 (80B, 16-aligned)
  #pragma unroll
  for (int i = 0; i < 4; ++i){
    *(uint4*)&Qs[lane*40 + i*8] = qa[i];
    *(uint4*)&Ks[lane*40 + i*8] = ka[i];
  }
  // stage V transposed+permuted: Vt[d][pi(n)] = V[n][d]
  int pn = (lane & 15) * 4 + (lane >> 4);
  #pragma unroll
  for (int d2 = 0; d2 < 16; ++d2){
    Vt[(2*d2  )*72 + pn] = (u16)(vu[d2] & 0xffff);
    Vt[(2*d2+1)*72 + pn] = (u16)(vu[d2] >> 16);
  }
  // ones rows 32..47 (row-sum trick)
  uint4 ones = {0x3F803F80u, 0x3F803F80u, 0x3F803F80u, 0x3F803F80u};
  *(uint4*)&Vt[(32 + (lane >> 3))*72 + (lane & 7)*8] = ones;
  *(uint4*)&Vt[(40 + (lane >> 3))*72 + (lane & 7)*8] = ones;

  int quad = lane >> 4, l16 = lane & 15;

  short8 qf[4], kf[4];
  #pragma unroll
  for (int i = 0; i < 4; ++i) qf[i] = *(const short8*)&Qs[(i*16 + l16)*40 + quad*8];
  #pragma unroll
  for (int j = 0; j < 4; ++j) kf[j] = *(const short8*)&Ks[(j*16 + l16)*40 + quad*8];

  f32x4 sa[4][4];
  #pragma unroll
  for (int i = 0; i < 4; ++i)
    #pragma unroll
    for (int j = 0; j < 4; ++j){
      #pragma unroll
      for (int rr = 0; rr < 4; ++rr) sa[i][j][rr] = 0.f;
      sa[i][j] = __builtin_amdgcn_mfma_f32_16x16x32_bf16(qf[i], kf[j], sa[i][j], 0, 0, 0);
    }

  // P = exp(S*scale) -> bf16 -> Ps (overlays Qs/Ks; Q/K frags already in regs).
  #pragma unroll
  for (int i = 0; i < 4; ++i)
    #pragma unroll
    for (int rr = 0; rr < 4; ++rr){
      float e0 = __expf(sa[i][0][rr] * SCALE_ATT);
      float e1 = __expf(sa[i][1][rr] * SCALE_ATT);
      float e2 = __expf(sa[i][2][rr] * SCALE_ATT);
      float e3 = __expf(sa[i][3][rr] * SCALE_ATT);
      uint2 pk;
      pk.x = (u32)f2bf(e0) | ((u32)f2bf(e1) << 16);
      pk.y = (u32)f2bf(e2) | ((u32)f2bf(e3) << 16);
      *(uint2*)&Ps[(i*16 + quad*4 + rr)*72 + l16*4] = pk;
    }

  // PV: P A-frags from Ps, V B-frags from Vt (both in pi-space), 2 k-steps of 32.
  f32x4 oa[4][2], os[4];
  #pragma unroll
  for (int i = 0; i < 4; ++i){
    #pragma unroll
    for (int rr = 0; rr < 4; ++rr){ oa[i][0][rr] = 0.f; oa[i][1][rr] = 0.f; os[i][rr] = 0.f; }
  }
  #pragma unroll
  for (int ks = 0; ks < 2; ++ks){
    short8 vf0 = *(const short8*)&Vt[(     l16)*72 + ks*32 + quad*8];
    short8 vf1 = *(const short8*)&Vt[(16 + l16)*72 + ks*32 + quad*8];
    short8 vf2 = *(const short8*)&Vt[(32 + l16)*72 + ks*32 + quad*8];
    #pragma unroll
    for (int i = 0; i < 4; ++i){
      short8 pf = *(const short8*)&Ps[(i*16 + l16)*72 + ks*32 + quad*8];
      oa[i][0] = __builtin_amdgcn_mfma_f32_16x16x32_bf16(pf, vf0, oa[i][0], 0, 0, 0);
      oa[i][1] = __builtin_amdgcn_mfma_f32_16x16x32_bf16(pf, vf1, oa[i][1], 0, 0, 0);
      os[i]    = __builtin_amdgcn_mfma_f32_16x16x32_bf16(pf, vf2, os[i],    0, 0, 0);
    }
  }

  // epilogue: O[m][d] = oa/rowsum; store bf16 at sorted position rank[token]
  int tb = b * 4096 + wy * 512 + wx * 8;
  #pragma unroll
  for (int i = 0; i < 4; ++i)
    #pragma unroll
    for (int rr = 0; rr < 4; ++rr){
      float inv = __builtin_amdgcn_rcpf(os[i][rr]);
      int m = i*16 + quad*4 + rr;
      int tm = tb + (m >> 3) * 64 + (m & 7);
      int pos = rank[tm];
      u16* op = attn_s + (size_t)pos * 256 + head * 32 + l16;
      op[0]  = f2bf(oa[i][0][rr] * inv);
      op[16] = f2bf(oa[i][1][rr] * inv);
    }
}

// ---------------- launch ----------------
extern "C" void kernel_launch(void* const* d_in, const int* in_sizes, int n_in,
                              void* d_out, int out_size, void* d_ws, size_t ws_size,
                              hipStream_t stream){
  const float* x     = (const float*)d_in[0];
  const float* rw1   = (const float*)d_in[1];
  const float* rb1   = (const float*)d_in[2];
  const float* rw2   = (const float*)d_in[3];
  const float* rb2   = (const float*)d_in[4];
  const float* qkvw  = (const float*)d_in[5];
  const float* qkvb  = (const float*)d_in[6];
  const float* projw = (const float*)d_in[7];
  const float* projb = (const float*)d_in[8];
  float* out = (float*)d_out;

  char* ws = (char*)d_ws;
  u16*   x_bf    = (u16*)(ws);                       // 16,777,216 B
  u16*   qkv_bf  = (u16*)(ws + 16777216);            // 50,331,648 B
  // shared region (disjoint lifetimes): w1 split (router) -> xs (qkv gemm)
  // -> attn_s (attn + proj gemm). 17,301,504 B (33792 rows x 512B).
  u16*   w1h     = (u16*)(ws + 67108864);
  u16*   w1l     = w1h + 32768;
  u16*   xs      = (u16*)(ws + 67108864);
  u16*   attn_s  = (u16*)(ws + 67108864);
  u16*   qw_bf   = (u16*)(ws + 84410368);            //  3,145,728 B
  u16*   pw_bf   = (u16*)(ws + 87556096);            //  1,048,576 B
  int*   routes  = (int*)(ws + 88604672);            //    131,072 B
  float* pmaxp   = (float*)(ws + 88735744);          //    131,072 B
  int*   sorted  = (int*)(ws + 88866816);            //    135,168 B (33792 slots)
  int*   rank    = (int*)(ws + 89001984);            //    131,072 B
  int*   counts  = (int*)(ws + 89133056);
  int*   cursors = (int*)(ws + 89133056 + 32);
  int*   offs    = (int*)(ws + 89133056 + 64);

  k_init<<<1, 64, 0, stream>>>(counts, cursors);
  k_cvt<<<1536, 256, 0, stream>>>(qkvw,  qw_bf, 1572864/4);
  k_cvt<<< 512, 256, 0, stream>>>(projw, pw_bf,  524288/4);
  k_cvt_split<<<128, 256, 0, stream>>>(rw1, w1h, w1l, 32768);
  k_router<<<512, 256, 0, stream>>>(x, w1h, w1l, rb1, rw2, rb2, routes, pmaxp, counts, x_bf);
  k_offsets<<<1, 256, 0, stream>>>(counts, offs, sorted);
  k_scatter<<<128, 256, 0, stream>>>(routes, offs, cursors, sorted, rank);
  k_gather<<<2112, 256, 0, stream>>>(x_bf, sorted, offs, xs);   // overwrites w1 split (dead)
  k_gemm<768, false><<<dim3(6, 264), 256, 0, stream>>>(xs, qw_bf, qkvb, sorted, offs,
                                                       nullptr, qkv_bf, nullptr);
  k_attn<<<2048, 128, 0, stream>>>(qkv_bf, rank, attn_s);       // overwrites xs (dead)
  k_gemm<256, true><<<dim3(2, 264), 256, 0, stream>>>(attn_s, pw_bf, projb, sorted, offs,
                                                      pmaxp, nullptr, out);
}